// Round 1
// baseline (919.898 us; speedup 1.0000x reference)
//
#include <hip/hip_runtime.h>

#define Nn 8192
#define Bb 4
#define KK 20
#define OO 64
#define EPSF 1e-5f
#define SLOPEF 0.2f

// ---------------- KNN: exact top-20 nearest (incl. self), ties -> lower index ----------------

__device__ __forceinline__ void qinsert(float cd, int ci, float bd[KK], int bi[KK]) {
  // bubble-insert into ascending-sorted queue; strict < keeps earlier-index on ties
  #pragma unroll
  for (int j = 0; j < KK; ++j) {
    bool sw = cd < bd[j];
    float td = bd[j]; int ti = bi[j];
    bd[j] = sw ? cd : td;
    bi[j] = sw ? ci : ti;
    cd = sw ? td : cd;
    ci = sw ? ti : ci;
  }
}

__global__ __launch_bounds__(128) void knn_kernel(const float* __restrict__ x,
                                                  int* __restrict__ idx_out) {
  // block = 128 threads = 2 waves; wave 0 scans m in [0,4096), wave 1 scans [4096,8192)
  // for the same 64 rows n. Merge at the end (low half is incumbent -> tie order correct).
  __shared__ float4 smx[2][1024];   // (x0,x1,x2,sq) per point, per segment tile
  __shared__ float  lmd[64][KK];
  __shared__ int    lmi[64][KK];

  const int b    = blockIdx.y;
  const int lane = threadIdx.x & 63;
  const int seg  = threadIdx.x >> 6;
  const int n    = blockIdx.x * 64 + lane;

  const float* xb = x + b * 3 * Nn;
  const float xn0 = xb[n], xn1 = xb[Nn + n], xn2 = xb[2 * Nn + n];
  const float sqn = xn0 * xn0 + xn1 * xn1 + xn2 * xn2;

  float bd[KK]; int bi[KK];
  #pragma unroll
  for (int k = 0; k < KK; ++k) { bd[k] = __builtin_inff(); bi[k] = -1; }
  float fb[4]; int fi[4]; int fcnt = 0;
  fb[0]=fb[1]=fb[2]=fb[3]=0.f; fi[0]=fi[1]=fi[2]=fi[3]=0;

  for (int ts = 0; ts < 4; ++ts) {
    // cooperative load of both segment tiles (coalesced per row of x)
    for (int t = threadIdx.x; t < 2048; t += 128) {
      int s = t >> 10, jj = t & 1023;
      int g = s * 4096 + ts * 1024 + jj;
      float a0 = xb[g], a1 = xb[Nn + g], a2 = xb[2 * Nn + g];
      smx[s][jj] = make_float4(a0, a1, a2, a0 * a0 + a1 * a1 + a2 * a2);
    }
    __syncthreads();
    const int mbase = seg * 4096 + ts * 1024;
    for (int j = 0; j < 1024; ++j) {
      float4 p = smx[seg][j];                       // broadcast read (all lanes same addr)
      float inner = xn0 * p.x + xn1 * p.y + xn2 * p.z;
      float d = sqn + p.w - 2.0f * inner;
      if (d < bd[KK - 1]) {                         // stale threshold is conservative (>= true 20th)
        #pragma unroll
        for (int s2 = 0; s2 < 4; ++s2) if (fcnt == s2) { fb[s2] = d; fi[s2] = mbase + j; }
        fcnt++;
      }
      if (__ballot(fcnt == 4)) {                    // wave-uniform flush: shared cost
        #pragma unroll
        for (int s2 = 0; s2 < 4; ++s2) if (s2 < fcnt) qinsert(fb[s2], fi[s2], bd, bi);
        fcnt = 0;
      }
    }
    __syncthreads();
  }
  // final flush
  #pragma unroll
  for (int s2 = 0; s2 < 4; ++s2) if (s2 < fcnt) qinsert(fb[s2], fi[s2], bd, bi);

  // merge the two half-range queues per row
  if (seg == 1) {
    #pragma unroll
    for (int k = 0; k < KK; ++k) { lmd[lane][k] = bd[k]; lmi[lane][k] = bi[k]; }
  }
  __syncthreads();
  if (seg == 0) {
    #pragma unroll
    for (int k = 0; k < KK; ++k) qinsert(lmd[lane][k], lmi[lane][k], bd, bi);
    int* op = idx_out + (b * Nn + n) * KK;
    #pragma unroll
    for (int k = 0; k < KK; ++k) op[k] = bi[k];
  }
}

// ---------------- u = (Wa-Wb)·x_n, v = Wb·x_n  (layout [b][n][o], o contiguous) -------------

__global__ __launch_bounds__(256) void uv_kernel(const float* __restrict__ x,
                                                 const float* __restrict__ W,
                                                 float* __restrict__ u,
                                                 float* __restrict__ v) {
  int gid = blockIdx.x * 256 + threadIdx.x;       // (b*N + n)*64 + o ; 2^21 threads
  int o  = gid & 63;
  int bn = gid >> 6;
  int b  = bn >> 13;
  int n  = bn & (Nn - 1);
  const float* xb = x + b * 3 * Nn;
  float x0 = xb[n], x1 = xb[Nn + n], x2 = xb[2 * Nn + n];
  float wa0 = W[o * 6 + 0], wa1 = W[o * 6 + 1], wa2 = W[o * 6 + 2];
  float wb0 = W[o * 6 + 3], wb1 = W[o * 6 + 4], wb2 = W[o * 6 + 5];
  u[gid] = (wa0 - wb0) * x0 + (wa1 - wb1) * x1 + (wa2 - wb2) * x2;
  v[gid] = wb0 * x0 + wb1 * x1 + wb2 * x2;
}

// ---------------- gather v over neighbors: pm = u + max_k v ; accumulate S1,S2 --------------

__global__ __launch_bounds__(256) void gather_kernel(const int* __restrict__ idx,
                                                     float* __restrict__ u,      // in-place -> pm
                                                     const float* __restrict__ v,
                                                     float* __restrict__ stats) {
  __shared__ float ls1[4][64], ls2[4][64];
  int b  = blockIdx.y;
  int o  = threadIdx.x & 63;
  int ys = threadIdx.x >> 6;
  const float* vb = v + (size_t)b * Nn * OO;
  float s1 = 0.f, s2 = 0.f;
  for (int i = 0; i < 16; ++i) {
    int n = blockIdx.x * 64 + ys * 16 + i;
    const int* ip = idx + (b * Nn + n) * KK;     // wave-uniform -> scalar loads
    float un = u[(size_t)(b * Nn + n) * OO + o];
    float sv = 0.f, sv2 = 0.f, mv = -__builtin_inff();
    #pragma unroll
    for (int k = 0; k < KK; ++k) {
      int j = ip[k];
      float val = vb[(size_t)j * OO + o];        // 256B coalesced per (n,k)
      sv += val; sv2 += val * val; mv = fmaxf(mv, val);
    }
    u[(size_t)(b * Nn + n) * OO + o] = un + mv;  // pm = max_k y (pre-norm)
    s1 += (float)KK * un + sv;
    s2 += (float)KK * un * un + 2.f * un * sv + sv2;
  }
  ls1[ys][o] = s1; ls2[ys][o] = s2;
  __syncthreads();
  if (ys == 0) {
    float t1 = ls1[0][o] + ls1[1][o] + ls1[2][o] + ls1[3][o];
    float t2 = ls2[0][o] + ls2[1][o] + ls2[2][o] + ls2[3][o];
    atomicAdd(&stats[(b * OO + o) * 2 + 0], t1);
    atomicAdd(&stats[(b * OO + o) * 2 + 1], t2);
  }
}

// ---------------- finalize: normalize + lrelu + transpose to [b][o][n] ----------------------

__global__ __launch_bounds__(256) void out_kernel(const float* __restrict__ pm,
                                                  const float* __restrict__ stats,
                                                  float* __restrict__ out) {
  __shared__ float tile[64][65];
  int b  = blockIdx.y;
  int o  = threadIdx.x & 63;
  int ys = threadIdx.x >> 6;
  const float inv_cnt = 1.0f / (float)(Nn * KK);
  float S1 = stats[(b * OO + o) * 2 + 0];
  float S2 = stats[(b * OO + o) * 2 + 1];
  float mean = S1 * inv_cnt;
  float var  = S2 * inv_cnt - mean * mean;
  float istd = rsqrtf(var + EPSF);
  for (int i = 0; i < 16; ++i) {
    int n = blockIdx.x * 64 + ys * 16 + i;
    float val = (pm[(size_t)(b * Nn + n) * OO + o] - mean) * istd;
    val = (val >= 0.f) ? val : SLOPEF * val;
    tile[ys * 16 + i][o] = val;
  }
  __syncthreads();
  int nb = blockIdx.x * 64;
  for (int i = 0; i < 16; ++i) {
    int oo = ys * 16 + i;
    out[(size_t)(b * OO + oo) * Nn + nb + o] = tile[o][oo];  // coalesced 256B writes
  }
}

// ---------------- launch ---------------------------------------------------------------------

extern "C" void kernel_launch(void* const* d_in, const int* in_sizes, int n_in,
                              void* d_out, int out_size, void* d_ws, size_t ws_size,
                              hipStream_t stream) {
  const float* x = (const float*)d_in[0];
  const float* W = (const float*)d_in[1];
  float* out = (float*)d_out;

  char* ws = (char*)d_ws;
  int*   idx   = (int*)ws;                                   // 4*8192*20*4  = 2,621,440 B
  float* u     = (float*)(ws + 2621440);                     // 4*8192*64*4  = 8,388,608 B (also pm)
  float* v     = (float*)(ws + 2621440 + 8388608);           // 8,388,608 B
  float* stats = (float*)(ws + 2621440 + 2 * 8388608);       // 4*64*2*4 = 2,048 B

  hipMemsetAsync(stats, 0, Bb * OO * 2 * sizeof(float), stream);
  knn_kernel   <<<dim3(128, Bb), 128, 0, stream>>>(x, idx);
  uv_kernel    <<<dim3((Bb * Nn * OO) / 256), 256, 0, stream>>>(x, W, u, v);
  gather_kernel<<<dim3(128, Bb), 256, 0, stream>>>(idx, u, v, stats);
  out_kernel   <<<dim3(128, Bb), 256, 0, stream>>>(u, stats, out);
}

// Round 2
// 506.154 us; speedup vs baseline: 1.8174x; 1.8174x over previous
//
#include <hip/hip_runtime.h>

#define Nn 8192
#define Bb 4
#define KK 20
#define OO 64
#define EPSF 1e-5f
#define SLOPEF 0.2f

// ---------------- pack: P[b][j] = (x,y,z, |x|^2) ------------------------------------------

__global__ __launch_bounds__(256) void pack_kernel(const float* __restrict__ x,
                                                   float4* __restrict__ P) {
  int gid = blockIdx.x * 256 + threadIdx.x;      // b*N + j
  int b = gid >> 13, j = gid & (Nn - 1);
  const float* xb = x + b * 3 * Nn;
  float a0 = xb[j], a1 = xb[Nn + j], a2 = xb[2 * Nn + j];
  P[gid] = make_float4(a0, a1, a2, a0 * a0 + a1 * a1 + a2 * a2);
}

// ---------------- KNN: exact top-20 (incl. self), ties -> lower index ----------------------

__device__ __forceinline__ void qinsert(float cd, int ci, float bd[KK], int bi[KK]) {
  #pragma unroll
  for (int j = 0; j < KK; ++j) {
    bool sw = cd < bd[j];
    float td = bd[j]; int ti = bi[j];
    bd[j] = sw ? cd : td;
    bi[j] = sw ? ci : ti;
    cd = sw ? td : cd;
    ci = sw ? ti : ci;
  }
}

// tie-aware variant for the tree merge (incoming indices not ordered vs incumbent)
__device__ __forceinline__ void qinsert_tie(float cd, int ci, float bd[KK], int bi[KK]) {
  #pragma unroll
  for (int j = 0; j < KK; ++j) {
    bool sw = (cd < bd[j]) || (cd == bd[j] && ci < bi[j]);
    float td = bd[j]; int ti = bi[j];
    bd[j] = sw ? cd : td;
    bi[j] = sw ? ci : ti;
    cd = sw ? td : cd;
    ci = sw ? ti : ci;
  }
}

__global__ __launch_bounds__(512, 4) void knn_kernel(const float4* __restrict__ P,
                                                     int* __restrict__ idx_out) {
  // 512 threads = 8 waves. Each wave scans its own 1024-point m-segment for the
  // same 64 rows (lane = row). Log-tree merge of the 8 queues at the end.
  __shared__ __align__(16) char ldsbuf[65536];
  float4 (*smx)[512]     = (float4 (*)[512])ldsbuf;                    // [8][512] tile
  float  (*lmd)[64][21]  = (float (*)[64][21])ldsbuf;                  // [4][64][21]
  int    (*lmi)[64][21]  = (int   (*)[64][21])(ldsbuf + 4 * 64 * 21 * 4);

  const int b    = blockIdx.y;
  const int lane = threadIdx.x & 63;
  const int wid  = threadIdx.x >> 6;
  const int n    = blockIdx.x * 64 + lane;

  const float4* Pb = P + b * Nn;
  const float4 me = Pb[n];
  const float xn0 = me.x, xn1 = me.y, xn2 = me.z, sqn = me.w;

  float bd[KK]; int bi[KK];
  #pragma unroll
  for (int k = 0; k < KK; ++k) { bd[k] = __builtin_inff(); bi[k] = -1; }
  float fb[4]; int fi[4]; int fcnt = 0;

  for (int ts = 0; ts < 2; ++ts) {
    __syncthreads();
    for (int t = threadIdx.x; t < 4096; t += 512) {
      int s = t >> 9, jj = t & 511;
      smx[s][jj] = Pb[s * 1024 + ts * 512 + jj];
    }
    __syncthreads();
    const int mbase = wid * 1024 + ts * 512;
    for (int j = 0; j < 512; j += 2) {
      float4 p0 = smx[wid][j];
      float4 p1 = smx[wid][j + 1];
      float d0 = sqn + p0.w - 2.0f * (xn0 * p0.x + xn1 * p0.y + xn2 * p0.z);
      float d1 = sqn + p1.w - 2.0f * (xn0 * p1.x + xn1 * p1.y + xn2 * p1.z);
      float thr = bd[KK - 1];
      if (d0 < thr) {
        #pragma unroll
        for (int s2 = 0; s2 < 4; ++s2) if (fcnt == s2) { fb[s2] = d0; fi[s2] = mbase + j; }
        fcnt++;
      }
      if (d1 < thr) {
        #pragma unroll
        for (int s2 = 0; s2 < 4; ++s2) if (fcnt == s2) { fb[s2] = d1; fi[s2] = mbase + j + 1; }
        fcnt++;
      }
      if (__ballot(fcnt >= 3)) {            // wave-uniform flush; invariant: fcnt <= 4 always
        #pragma unroll
        for (int s2 = 0; s2 < 4; ++s2) if (s2 < fcnt) qinsert(fb[s2], fi[s2], bd, bi);
        fcnt = 0;
      }
    }
  }
  // final flush
  #pragma unroll
  for (int s2 = 0; s2 < 4; ++s2) if (s2 < fcnt) qinsert(fb[s2], fi[s2], bd, bi);

  // ---- log-tree merge: 8 -> 4 -> 2 -> 1 (reuses tile LDS) ----
  for (int stride = 4; stride >= 1; stride >>= 1) {
    __syncthreads();
    if (wid >= stride && wid < 2 * stride) {
      #pragma unroll
      for (int k = 0; k < KK; ++k) { lmd[wid - stride][lane][k] = bd[k]; lmi[wid - stride][lane][k] = bi[k]; }
    }
    __syncthreads();
    if (wid < stride) {
      #pragma unroll
      for (int k = 0; k < KK; ++k) {
        float cd = lmd[wid][lane][k]; int ci = lmi[wid][lane][k];
        if (!__ballot(cd < bd[KK - 1] || (cd == bd[KK - 1] && ci < bi[KK - 1]))) break;
        qinsert_tie(cd, ci, bd, bi);
      }
    }
  }
  if (wid == 0) {
    int* op = idx_out + (b * Nn + n) * KK;
    #pragma unroll
    for (int k = 0; k < KK; ++k) op[k] = bi[k];
  }
}

// ---------------- u = (Wa-Wb)·x_n, v = Wb·x_n  (layout [b][n][o], o contiguous) -------------

__global__ __launch_bounds__(256) void uv_kernel(const float* __restrict__ x,
                                                 const float* __restrict__ W,
                                                 float* __restrict__ u,
                                                 float* __restrict__ v) {
  int gid = blockIdx.x * 256 + threadIdx.x;
  int o  = gid & 63;
  int bn = gid >> 6;
  int b  = bn >> 13;
  int n  = bn & (Nn - 1);
  const float* xb = x + b * 3 * Nn;
  float x0 = xb[n], x1 = xb[Nn + n], x2 = xb[2 * Nn + n];
  float wa0 = W[o * 6 + 0], wa1 = W[o * 6 + 1], wa2 = W[o * 6 + 2];
  float wb0 = W[o * 6 + 3], wb1 = W[o * 6 + 4], wb2 = W[o * 6 + 5];
  u[gid] = (wa0 - wb0) * x0 + (wa1 - wb1) * x1 + (wa2 - wb2) * x2;
  v[gid] = wb0 * x0 + wb1 * x1 + wb2 * x2;
}

// ---------------- gather v over neighbors: pm = u + max_k v ; accumulate S1,S2 --------------

__global__ __launch_bounds__(256) void gather_kernel(const int* __restrict__ idx,
                                                     float* __restrict__ u,      // in-place -> pm
                                                     const float* __restrict__ v,
                                                     float* __restrict__ stats) {
  __shared__ float ls1[4][64], ls2[4][64];
  int b  = blockIdx.y;
  int o  = threadIdx.x & 63;
  int ys = threadIdx.x >> 6;
  const float* vb = v + (size_t)b * Nn * OO;
  float s1 = 0.f, s2 = 0.f;
  for (int i = 0; i < 16; ++i) {
    int n = blockIdx.x * 64 + ys * 16 + i;
    const int* ip = idx + (b * Nn + n) * KK;
    float un = u[(size_t)(b * Nn + n) * OO + o];
    float sv = 0.f, sv2 = 0.f, mv = -__builtin_inff();
    #pragma unroll
    for (int k = 0; k < KK; ++k) {
      int j = ip[k];
      float val = vb[(size_t)j * OO + o];
      sv += val; sv2 += val * val; mv = fmaxf(mv, val);
    }
    u[(size_t)(b * Nn + n) * OO + o] = un + mv;
    s1 += (float)KK * un + sv;
    s2 += (float)KK * un * un + 2.f * un * sv + sv2;
  }
  ls1[ys][o] = s1; ls2[ys][o] = s2;
  __syncthreads();
  if (ys == 0) {
    float t1 = ls1[0][o] + ls1[1][o] + ls1[2][o] + ls1[3][o];
    float t2 = ls2[0][o] + ls2[1][o] + ls2[2][o] + ls2[3][o];
    atomicAdd(&stats[(b * OO + o) * 2 + 0], t1);
    atomicAdd(&stats[(b * OO + o) * 2 + 1], t2);
  }
}

// ---------------- finalize: normalize + lrelu + transpose to [b][o][n] ----------------------

__global__ __launch_bounds__(256) void out_kernel(const float* __restrict__ pm,
                                                  const float* __restrict__ stats,
                                                  float* __restrict__ out) {
  __shared__ float tile[64][65];
  int b  = blockIdx.y;
  int o  = threadIdx.x & 63;
  int ys = threadIdx.x >> 6;
  const float inv_cnt = 1.0f / (float)(Nn * KK);
  float S1 = stats[(b * OO + o) * 2 + 0];
  float S2 = stats[(b * OO + o) * 2 + 1];
  float mean = S1 * inv_cnt;
  float var  = S2 * inv_cnt - mean * mean;
  float istd = rsqrtf(var + EPSF);
  for (int i = 0; i < 16; ++i) {
    int n = blockIdx.x * 64 + ys * 16 + i;
    float val = (pm[(size_t)(b * Nn + n) * OO + o] - mean) * istd;
    val = (val >= 0.f) ? val : SLOPEF * val;
    tile[ys * 16 + i][o] = val;
  }
  __syncthreads();
  int nb = blockIdx.x * 64;
  for (int i = 0; i < 16; ++i) {
    int oo = ys * 16 + i;
    out[(size_t)(b * OO + oo) * Nn + nb + o] = tile[o][oo];
  }
}

// ---------------- launch ---------------------------------------------------------------------

extern "C" void kernel_launch(void* const* d_in, const int* in_sizes, int n_in,
                              void* d_out, int out_size, void* d_ws, size_t ws_size,
                              hipStream_t stream) {
  const float* x = (const float*)d_in[0];
  const float* W = (const float*)d_in[1];
  float* out = (float*)d_out;

  char* ws = (char*)d_ws;
  int*    idx   = (int*)ws;                                  // 2,621,440 B
  float*  u     = (float*)(ws + 2621440);                    // 8,388,608 B (becomes pm)
  float*  v     = (float*)(ws + 2621440 + 8388608);          // 8,388,608 B
  float*  stats = (float*)(ws + 2621440 + 2 * 8388608);      // 2,048 B
  float4* P     = (float4*)(ws + 2621440 + 2 * 8388608 + 4096); // 524,288 B

  hipMemsetAsync(stats, 0, Bb * OO * 2 * sizeof(float), stream);
  pack_kernel  <<<dim3((Bb * Nn) / 256), 256, 0, stream>>>(x, P);
  knn_kernel   <<<dim3(128, Bb), 512, 0, stream>>>(P, idx);
  uv_kernel    <<<dim3((Bb * Nn * OO) / 256), 256, 0, stream>>>(x, W, u, v);
  gather_kernel<<<dim3(128, Bb), 256, 0, stream>>>(idx, u, v, stats);
  out_kernel   <<<dim3(128, Bb), 256, 0, stream>>>(u, stats, out);
}